// Round 3
// baseline (72.408 us; speedup 1.0000x reference)
//
#include <hip/hip_runtime.h>

#define N_QUBITS 4
#define N_LAYERS 6
#define NSTATES  16   // 2^N_QUBITS
#define SPT      4    // samples per thread in the apply kernel

__device__ __forceinline__ float2 cmul(float2 a, float2 b) {
    return make_float2(a.x * b.x - a.y * b.y, a.x * b.y + a.y * b.x);
}
__device__ __forceinline__ float2 cadd(float2 a, float2 b) {
    return make_float2(a.x + b.x, a.y + b.y);
}

// ---------------------------------------------------------------------------
// Build kernel: ONE wave (64 threads), zero barrier ladder.
//   lanes 0..23 : compute the 24 Rot gate matrices -> LDS (one 1-wave sync)
//   lanes 0..15 : each evolves ONE column of U entirely in registers
//                 (16 x float2); CNOT ring = compile-time register permutation.
// U row-major interleaved re/im: U[2*(i*16+c)+{0,1}] = <i|U|c>.
// ---------------------------------------------------------------------------
__global__ __launch_bounds__(64) void build_u_kernel(
        const float* __restrict__ weights, float* __restrict__ U) {
    __shared__ float2 rotm[N_LAYERS * N_QUBITS][4];

    const int t = threadIdx.x;
    if (t < N_LAYERS * N_QUBITS) {
        const float phi   = weights[t * 3 + 0];
        const float theta = weights[t * 3 + 1];
        const float omega = weights[t * 3 + 2];
        float stheta, ctheta;
        sincosf(theta * 0.5f, &stheta, &ctheta);
        const float a1 = -(phi + omega) * 0.5f;
        const float a2 =  (phi - omega) * 0.5f;
        float s1, c1, s2, c2;
        sincosf(a1, &s1, &c1);
        sincosf(a2, &s2, &c2);
        rotm[t][0] = make_float2( c1 * ctheta,  s1 * ctheta);   // m00
        rotm[t][1] = make_float2(-c2 * stheta, -s2 * stheta);   // m01
        rotm[t][2] = make_float2( c2 * stheta, -s2 * stheta);   // m10
        rotm[t][3] = make_float2( c1 * ctheta, -s1 * ctheta);   // m11
    }
    __syncthreads();   // single-wave block: essentially just a waitcnt

    if (t < NSTATES) {
        const int c = t;                 // this lane's column
        float2 s[NSTATES];
        #pragma unroll
        for (int q = 0; q < NSTATES; ++q)
            s[q] = make_float2(q == c ? 1.0f : 0.0f, 0.0f);

        #pragma unroll
        for (int l = 0; l < N_LAYERS; ++l) {
            #pragma unroll
            for (int w = 0; w < N_QUBITS; ++w) {
                const float2 m00 = rotm[l * N_QUBITS + w][0];
                const float2 m01 = rotm[l * N_QUBITS + w][1];
                const float2 m10 = rotm[l * N_QUBITS + w][2];
                const float2 m11 = rotm[l * N_QUBITS + w][3];
                const int bit = 8 >> w;
                #pragma unroll
                for (int i = 0; i < NSTATES; ++i) {
                    if (i & bit) continue;
                    const int j = i | bit;
                    const float2 a0 = s[i];
                    const float2 a1v = s[j];
                    s[i] = cadd(cmul(m00, a0), cmul(m01, a1v));
                    s[j] = cadd(cmul(m10, a0), cmul(m11, a1v));
                }
            }
            const int r = l % (N_QUBITS - 1) + 1;
            float2 tmp[NSTATES];
            #pragma unroll
            for (int i = 0; i < NSTATES; ++i) {
                int fi = i;
                #pragma unroll
                for (int w = 0; w < N_QUBITS; ++w) {
                    const int tb = 8 >> ((w + r) & 3);
                    if ((fi >> (3 - w)) & 1) fi ^= tb;   // CNOT: target ^= control
                }
                tmp[fi] = s[i];
            }
            #pragma unroll
            for (int i = 0; i < NSTATES; ++i) s[i] = tmp[i];
        }

        #pragma unroll
        for (int i = 0; i < NSTATES; ++i)
            reinterpret_cast<float2*>(U)[i * NSTATES + c] = s[i];
    }
}

// ---------------------------------------------------------------------------
// Apply kernel, SPT samples per thread: each U row (8 x float4, wave-uniform,
// L1-resident) is loaded ONCE and reused by SPT samples -> L1 traffic drops
// from B*2KB (512 MB) to B/SPT*2KB (128 MB), which R2's counters identified
// as the bottleneck. Signs folded into the row loop; all indices compile-time.
// ---------------------------------------------------------------------------
template<bool GUARD>
__global__ __launch_bounds__(256) void qc_apply_kernel(
        const float* __restrict__ inputs,   // (B, 4)
        const float* __restrict__ U,        // 16x16 complex, interleaved
        float* __restrict__ out,            // (B, 4)
        int B) {
    const int base = blockIdx.x * (256 * SPT) + threadIdx.x;  // sample s at base + s*256

    // --- per-sample RY product state v (real) ---
    float v[SPT][NSTATES];
    bool live[SPT];
    #pragma unroll
    for (int s = 0; s < SPT; ++s) {
        const int b = base + s * 256;
        live[s] = !GUARD || (b < B);
        const float4 xin = live[s] ? reinterpret_cast<const float4*>(inputs)[b]
                                   : make_float4(0.f, 0.f, 0.f, 0.f);
        float s0, c0, s1, c1, s2, c2, s3, c3;
        __sincosf(xin.x * 0.5f, &s0, &c0);
        __sincosf(xin.y * 0.5f, &s1, &c1);
        __sincosf(xin.z * 0.5f, &s2, &c2);
        __sincosf(xin.w * 0.5f, &s3, &c3);
        const float vA[4] = { c0 * c1, c0 * s1, s0 * c1, s0 * s1 };  // wires 0,1
        const float vB[4] = { c2 * c3, c2 * s3, s2 * c3, s2 * s3 };  // wires 2,3
        #pragma unroll
        for (int a = 0; a < 4; ++a)
            #pragma unroll
            for (int q = 0; q < 4; ++q)
                v[s][a * 4 + q] = vA[a] * vB[q];
    }

    float z[SPT][4];
    #pragma unroll
    for (int s = 0; s < SPT; ++s)
        #pragma unroll
        for (int w = 0; w < 4; ++w) z[s][w] = 0.0f;

    #pragma unroll
    for (int i = 0; i < NSTATES; ++i) {
        const float4* row = reinterpret_cast<const float4*>(U + 2 * NSTATES * i);
        float4 u4[8];
        #pragma unroll
        for (int q = 0; q < 8; ++q) u4[q] = row[q];   // one load, SPT reuses

        #pragma unroll
        for (int s = 0; s < SPT; ++s) {
            float re = 0.0f, im = 0.0f;
            #pragma unroll
            for (int q = 0; q < 8; ++q) {             // 8 float4 = 16 complex
                re = fmaf(u4[q].x, v[s][2 * q],     re);
                im = fmaf(u4[q].y, v[s][2 * q],     im);
                re = fmaf(u4[q].z, v[s][2 * q + 1], re);
                im = fmaf(u4[q].w, v[s][2 * q + 1], im);
            }
            const float p = re * re + im * im;
            // z_w = sum_i (1 - 2*bit_{3-w}(i)) * p[i]; i compile-time
            z[s][0] = (i & 8) ? z[s][0] - p : z[s][0] + p;
            z[s][1] = (i & 4) ? z[s][1] - p : z[s][1] + p;
            z[s][2] = (i & 2) ? z[s][2] - p : z[s][2] + p;
            z[s][3] = (i & 1) ? z[s][3] - p : z[s][3] + p;
        }
    }

    #pragma unroll
    for (int s = 0; s < SPT; ++s) {
        const int b = base + s * 256;
        if (!GUARD || live[s])
            reinterpret_cast<float4*>(out)[b] =
                make_float4(z[s][0], z[s][1], z[s][2], z[s][3]);
    }
}

extern "C" void kernel_launch(void* const* d_in, const int* in_sizes, int n_in,
                              void* d_out, int out_size, void* d_ws, size_t ws_size,
                              hipStream_t stream) {
    const float* inputs  = (const float*)d_in[0];   // (B, 4) float32
    const float* weights = (const float*)d_in[1];   // (6, 4, 3) float32
    float* out = (float*)d_out;                     // (B, 4) float32
    float* U   = (float*)d_ws;                      // 512 floats scratch
    const int B = in_sizes[0] / N_QUBITS;

    build_u_kernel<<<1, 64, 0, stream>>>(weights, U);

    const int per_block = 256 * SPT;
    if (B % per_block == 0) {
        qc_apply_kernel<false><<<B / per_block, 256, 0, stream>>>(inputs, U, out, B);
    } else {
        qc_apply_kernel<true><<<(B + per_block - 1) / per_block, 256, 0, stream>>>(inputs, U, out, B);
    }
}

// Round 4
// 70.050 us; speedup vs baseline: 1.0337x; 1.0337x over previous
//
#include <hip/hip_runtime.h>

#define N_QUBITS 4
#define N_LAYERS 6
#define NSTATES  16   // 2^N_QUBITS
#define SPT      4    // samples per thread
#define BLOCK    256
#define NWAVES   (BLOCK / 64)

// ---------------------------------------------------------------------------
// Compile-time gather tables for the CNOT-ring permutations (r = 1,2,3).
// Forward map FW(i): apply CNOT(w, (w+r)%4) for w=0..3 to basis label i
// (wire w = bit (3-w)).  Scatter new[FW(i)] = old[i]  ==  gather
// new[j] = old[g[j]] with g[FW(i)] = i.  constexpr => indices are formally
// constant expressions => the register arrays below can never spill to
// scratch via runtime indexing (rule #20 protection).
// ---------------------------------------------------------------------------
struct PermT { int g[3][NSTATES]; };
constexpr PermT make_perm() {
    PermT p{};
    for (int r = 1; r <= 3; ++r)
        for (int i = 0; i < NSTATES; ++i) {
            int fi = i;
            for (int w = 0; w < 4; ++w) {
                const int tb = 8 >> ((w + r) & 3);
                if ((fi >> (3 - w)) & 1) fi ^= tb;   // CNOT: target ^= control
            }
            p.g[r - 1][fi] = i;
        }
    return p;
}
__device__ constexpr PermT PERM = make_perm();

__device__ __forceinline__ float2 cmul(float2 a, float2 b) {
    return make_float2(a.x * b.x - a.y * b.y, a.x * b.y + a.y * b.x);
}
__device__ __forceinline__ float2 cadd(float2 a, float2 b) {
    return make_float2(a.x + b.x, a.y + b.y);
}

// ---------------------------------------------------------------------------
// Single fused kernel, ZERO barriers.
// Per wave (redundant across waves, parallel across CUs):
//   lanes 0..23: 24 Rot matrices -> rotm[wave]           (LDS, intra-wave)
//   lanes 0..15: evolve one column of U in 16 float2 registers, constexpr
//                CNOT permutation, write column -> Um[wave]  (LDS)
//   all lanes  : SPT-sample apply reading U rows as wave-uniform
//                ds_read_b128 broadcasts (conflict-free).
// Intra-wave LDS write->read ordering is guaranteed by lgkmcnt waits the
// compiler inserts; no __syncthreads anywhere.
// ---------------------------------------------------------------------------
template<bool GUARD>
__global__ __launch_bounds__(BLOCK) void qc_fused_kernel(
        const float* __restrict__ inputs,   // (B, 4)
        const float* __restrict__ weights,  // (6, 4, 3)
        float* __restrict__ out,            // (B, 4)
        int B) {
    __shared__ float2 rotm[NWAVES][N_LAYERS * N_QUBITS][4];
    __shared__ __align__(16) float2 Um[NWAVES][NSTATES][NSTATES]; // [wave][row][col]

    const int tid  = threadIdx.x;
    const int wv   = tid >> 6;
    const int lane = tid & 63;

    // ---- phase 1a: gate matrices (lanes 0..23 of every wave) ----
    if (lane < N_LAYERS * N_QUBITS) {
        const float phi   = weights[lane * 3 + 0];
        const float theta = weights[lane * 3 + 1];
        const float omega = weights[lane * 3 + 2];
        float stheta, ctheta;
        sincosf(theta * 0.5f, &stheta, &ctheta);
        const float a1 = -(phi + omega) * 0.5f;
        const float a2 =  (phi - omega) * 0.5f;
        float s1, c1, s2, c2;
        sincosf(a1, &s1, &c1);
        sincosf(a2, &s2, &c2);
        rotm[wv][lane][0] = make_float2( c1 * ctheta,  s1 * ctheta);   // m00
        rotm[wv][lane][1] = make_float2(-c2 * stheta, -s2 * stheta);   // m01
        rotm[wv][lane][2] = make_float2( c2 * stheta, -s2 * stheta);   // m10
        rotm[wv][lane][3] = make_float2( c1 * ctheta, -s1 * ctheta);   // m11
    }

    // ---- phase 1b: column build in registers (lanes 0..15 of every wave) ----
    if (lane < NSTATES) {
        const int c = lane;
        float2 s[NSTATES];
        #pragma unroll
        for (int q = 0; q < NSTATES; ++q)
            s[q] = make_float2(q == c ? 1.0f : 0.0f, 0.0f);

        #pragma unroll
        for (int l = 0; l < N_LAYERS; ++l) {
            #pragma unroll
            for (int w = 0; w < N_QUBITS; ++w) {
                const float2 m00 = rotm[wv][l * N_QUBITS + w][0];
                const float2 m01 = rotm[wv][l * N_QUBITS + w][1];
                const float2 m10 = rotm[wv][l * N_QUBITS + w][2];
                const float2 m11 = rotm[wv][l * N_QUBITS + w][3];
                const int bit = 8 >> w;
                #pragma unroll
                for (int i = 0; i < NSTATES; ++i) {
                    if (i & bit) continue;
                    const int j = i | bit;
                    const float2 a0  = s[i];
                    const float2 a1v = s[j];
                    s[i] = cadd(cmul(m00, a0), cmul(m01, a1v));
                    s[j] = cadd(cmul(m10, a0), cmul(m11, a1v));
                }
            }
            // CNOT ring via constexpr gather table: all indices constant.
            const int rr = l % (N_QUBITS - 1);   // 0..2, literal after unroll
            float2 ns[NSTATES];
            #pragma unroll
            for (int j = 0; j < NSTATES; ++j) ns[j] = s[PERM.g[rr][j]];
            #pragma unroll
            for (int j = 0; j < NSTATES; ++j) s[j] = ns[j];
        }

        // write column c of U: Um[wv][i][c]
        #pragma unroll
        for (int i = 0; i < NSTATES; ++i)
            Um[wv][i][c] = s[i];
    }
    // No barrier: all Um/rotm producers and consumers are in the same wave;
    // the compiler's lgkmcnt waits order the LDS accesses.

    // ---- phase 2: apply, SPT samples per thread ----
    const int base = blockIdx.x * (BLOCK * SPT) + tid;   // sample s at base + s*BLOCK

    float v[SPT][NSTATES];
    bool live[SPT];
    #pragma unroll
    for (int s = 0; s < SPT; ++s) {
        const int b = base + s * BLOCK;
        live[s] = !GUARD || (b < B);
        const float4 xin = live[s] ? reinterpret_cast<const float4*>(inputs)[b]
                                   : make_float4(0.f, 0.f, 0.f, 0.f);
        float s0, c0, s1, c1, s2, c2, s3, c3;
        __sincosf(xin.x * 0.5f, &s0, &c0);
        __sincosf(xin.y * 0.5f, &s1, &c1);
        __sincosf(xin.z * 0.5f, &s2, &c2);
        __sincosf(xin.w * 0.5f, &s3, &c3);
        const float vA[4] = { c0 * c1, c0 * s1, s0 * c1, s0 * s1 };  // wires 0,1
        const float vB[4] = { c2 * c3, c2 * s3, s2 * c3, s2 * s3 };  // wires 2,3
        #pragma unroll
        for (int a = 0; a < 4; ++a)
            #pragma unroll
            for (int q = 0; q < 4; ++q)
                v[s][a * 4 + q] = vA[a] * vB[q];
    }

    float z[SPT][4];
    #pragma unroll
    for (int s = 0; s < SPT; ++s)
        #pragma unroll
        for (int w = 0; w < 4; ++w) z[s][w] = 0.0f;

    #pragma unroll
    for (int i = 0; i < NSTATES; ++i) {
        // row i of U: 128 B contiguous in LDS, wave-uniform address -> broadcast
        const float4* row = reinterpret_cast<const float4*>(&Um[wv][i][0]);
        float4 u4[8];
        #pragma unroll
        for (int q = 0; q < 8; ++q) u4[q] = row[q];

        #pragma unroll
        for (int s = 0; s < SPT; ++s) {
            float re = 0.0f, im = 0.0f;
            #pragma unroll
            for (int q = 0; q < 8; ++q) {          // 8 float4 = 16 complex
                re = fmaf(u4[q].x, v[s][2 * q],     re);
                im = fmaf(u4[q].y, v[s][2 * q],     im);
                re = fmaf(u4[q].z, v[s][2 * q + 1], re);
                im = fmaf(u4[q].w, v[s][2 * q + 1], im);
            }
            const float p = re * re + im * im;
            // z_w = sum_i (1 - 2*bit_{3-w}(i)) * p[i]; i compile-time
            z[s][0] = (i & 8) ? z[s][0] - p : z[s][0] + p;
            z[s][1] = (i & 4) ? z[s][1] - p : z[s][1] + p;
            z[s][2] = (i & 2) ? z[s][2] - p : z[s][2] + p;
            z[s][3] = (i & 1) ? z[s][3] - p : z[s][3] + p;
        }
    }

    #pragma unroll
    for (int s = 0; s < SPT; ++s) {
        const int b = base + s * BLOCK;
        if (!GUARD || live[s])
            reinterpret_cast<float4*>(out)[b] =
                make_float4(z[s][0], z[s][1], z[s][2], z[s][3]);
    }
}

extern "C" void kernel_launch(void* const* d_in, const int* in_sizes, int n_in,
                              void* d_out, int out_size, void* d_ws, size_t ws_size,
                              hipStream_t stream) {
    const float* inputs  = (const float*)d_in[0];   // (B, 4) float32
    const float* weights = (const float*)d_in[1];   // (6, 4, 3) float32
    float* out = (float*)d_out;                     // (B, 4) float32
    const int B = in_sizes[0] / N_QUBITS;

    const int per_block = BLOCK * SPT;
    if (B % per_block == 0) {
        qc_fused_kernel<false><<<B / per_block, BLOCK, 0, stream>>>(inputs, weights, out, B);
    } else {
        qc_fused_kernel<true><<<(B + per_block - 1) / per_block, BLOCK, 0, stream>>>(inputs, weights, out, B);
    }
}